// Round 10
// baseline (115.801 us; speedup 1.0000x reference)
//
#include <hip/hip_runtime.h>
#include <hip/hip_bf16.h>

#define T_ 8
#define N0_ 32
#define N1_ 32
#define SP_ (N0_*N1_)   /* 1024 spatial cells */
#define S_ (T_*SP_)     /* 8192 space-time cells */
#define E_ 256
#define P_ 16
#define NH_ 8
#define HD_ 32

typedef __attribute__((ext_vector_type(8))) short short8;
typedef __attribute__((ext_vector_type(4))) float f32x4;
typedef __attribute__((ext_vector_type(8))) unsigned short u16x8;

__device__ __forceinline__ unsigned short f2bf(float f) {
  __hip_bfloat16 h = __float2bfloat16(f);
  return *reinterpret_cast<unsigned short*>(&h);
}
__device__ __forceinline__ float bf2f(unsigned short u) {
  return __uint_as_float((unsigned)u << 16);
}

// async global->LDS, 16B per lane; dst = wave-uniform base + lane*16
__device__ __forceinline__ void gl_lds16(const unsigned short* g, unsigned short* l) {
  __builtin_amdgcn_global_load_lds(
      (const __attribute__((address_space(1))) unsigned int*)(g),
      (__attribute__((address_space(3))) unsigned int*)(l), 16, 0, 0);
}

// ---------------- stats: xmin & spacing per batch (matches reference fp32 ops) ------------
__global__ void stats_kernel(const float* __restrict__ tg, const float* __restrict__ grid,
                             float* __restrict__ stats, int m) {
  int lane = threadIdx.x;  // 64 threads, 1 block
  float mn0 = 1e30f, mx0 = -1e30f, mn1 = 1e30f, mx1 = -1e30f;
  for (int i = lane; i < SP_; i += 64) {
    float g0 = grid[i*2], g1 = grid[i*2+1];
    mn0 = fminf(mn0, g0); mx0 = fmaxf(mx0, g0);
    mn1 = fminf(mn1, g1); mx1 = fmaxf(mx1, g1);
  }
  for (int msk = 32; msk; msk >>= 1) {
    mn0 = fminf(mn0, __shfl_xor(mn0, msk));
    mx0 = fmaxf(mx0, __shfl_xor(mx0, msk));
    mn1 = fminf(mn1, __shfl_xor(mn1, msk));
    mx1 = fmaxf(mx1, __shfl_xor(mx1, msk));
  }
  if (lane == 0) {
    for (int b = 0; b < m; ++b) {
      float tmn = 1e30f, tmx = -1e30f;
      for (int t = 0; t < T_; ++t) {
        float v = tg[b*T_ + t];
        tmn = fminf(tmn, v); tmx = fmaxf(tmx, v);
      }
      float* st = stats + b*8;
      st[0] = tmn; st[1] = mn0; st[2] = mn1;
      st[3] = (tmx - tmn) / (float)(T_ - 1);
      st[4] = (mx0 - mn0) / (float)(N0_ - 1);
      st[5] = (mx1 - mn1) / (float)(N1_ - 1);
    }
  }
}

// ---------------- x_grid output ------------------------------------------------------------
__global__ void xgrid_kernel(const float* __restrict__ tg, const float* __restrict__ grid,
                             float* __restrict__ out, int total) {
  int idx = blockIdx.x * blockDim.x + threadIdx.x;  // over m*T*1024
  if (idx >= total) return;
  int sp = idx & (SP_ - 1);
  int bt = idx >> 10;
  out[idx*3 + 0] = tg[bt];
  out[idx*3 + 1] = grid[sp*2 + 0];
  out[idx*3 + 2] = grid[sp*2 + 1];
}

// ---------------- fp32 -> bf16 streaming convert ------------------------------------------
__global__ __launch_bounds__(256) void cvt_kernel(const float* __restrict__ in,
                                                  unsigned short* __restrict__ out, int n8) {
  int stride = gridDim.x * blockDim.x;
  for (int i = blockIdx.x * blockDim.x + threadIdx.x; i < n8; i += stride) {
    float4 a = *(const float4*)(in + (size_t)i * 8);
    float4 b = *(const float4*)(in + (size_t)i * 8 + 4);
    u16x8 o;
    o[0]=f2bf(a.x); o[1]=f2bf(a.y); o[2]=f2bf(a.z); o[3]=f2bf(a.w);
    o[4]=f2bf(b.x); o[5]=f2bf(b.y); o[6]=f2bf(b.z); o[7]=f2bf(b.w);
    *(u16x8*)(out + (size_t)i * 8) = o;
  }
}

// ---------------- point -> cell assignment (fp32 op order == reference) --------------------
__global__ void assign_kernel(const float* __restrict__ x, const float* __restrict__ stats,
                              int* __restrict__ counts, int* __restrict__ cell_raw,
                              int m, int n) {
  int i = blockIdx.x * blockDim.x + threadIdx.x;
  if (i >= m*n) return;
  int b = i / n;
  int j = i - b*n;
  const float* st = stats + b*8;
  float xt = x[(size_t)i*3 + 0], x0 = x[(size_t)i*3 + 1], x1 = x[(size_t)i*3 + 2];
  float m0 = floorf((xt - st[0] + st[3]*0.5f) / st[3]);
  float m1 = floorf((x0 - st[1] + st[4]*0.5f) / st[4]);
  float m2 = floorf((x1 - st[2] + st[5]*0.5f) / st[5]);
  m0 = fminf(fmaxf(m0, 0.f), (float)(T_ - 1));
  m1 = fminf(fmaxf(m1, 0.f), (float)(N0_ - 1));
  m2 = fminf(fmaxf(m2, 0.f), (float)(N1_ - 1));
  int s = (int)m0 * SP_ + (int)m1 * N1_ + (int)m2;
  int cg = b * S_ + s;
  int old = atomicAdd(&counts[cg], 1);
  if (old < P_) cell_raw[(size_t)cg * P_ + old] = j;
}

// ------- per-cell: sort indices (determinism + exact first-15 drop), pack eff+pts ---------
__global__ void finalize_kernel(const int* __restrict__ counts, int* __restrict__ cell_raw,
                                int* __restrict__ pts2, int total) {
  int cg = blockIdx.x * blockDim.x + threadIdx.x;
  if (cg >= total) return;
  int cnt = counts[cg];
  int stored = cnt < P_ ? cnt : P_;
  int eff = cnt < (P_ - 1) ? cnt : (P_ - 1);
  int* p = cell_raw + (size_t)cg * P_;
  for (int i = 1; i < stored; ++i) {   // insertion sort ascending (original index order)
    int key = p[i]; int j = i - 1;
    while (j >= 0 && p[j] > key) { p[j+1] = p[j]; --j; }
    p[j+1] = key;
  }
  int* o = pts2 + (size_t)cg * P_;
  o[0] = eff;
  for (int i = 0; i < eff; ++i) o[1 + i] = p[i];
}

// ---------------- weight transpose+convert: wT[1024][256] bf16 = [Wq|Wk|Wv|Wo]^T ----------
__global__ __launch_bounds__(256) void wtrans_kernel(const float* __restrict__ Wq,
                                                     const float* __restrict__ Wk,
                                                     const float* __restrict__ Wv,
                                                     const float* __restrict__ Wo,
                                                     unsigned short* __restrict__ wT) {
  int mat = blockIdx.x >> 4;
  int tile = blockIdx.x & 15;
  int tr = (tile >> 2) * 64;   // row (k) offset in W
  int tc = (tile & 3) * 64;    // col offset in W
  const float* W = mat == 0 ? Wq : mat == 1 ? Wk : mat == 2 ? Wv : Wo;
  __shared__ float ts[64][65];
  int t = threadIdx.x;
  int r = t >> 2, c0 = (t & 3) * 16;
#pragma unroll
  for (int i = 0; i < 4; ++i) {
    float4 v = *(const float4*)&W[(size_t)(tr + r) * 256 + tc + c0 + i*4];
    ts[r][c0 + i*4 + 0] = v.x; ts[r][c0 + i*4 + 1] = v.y;
    ts[r][c0 + i*4 + 2] = v.z; ts[r][c0 + i*4 + 3] = v.w;
  }
  __syncthreads();
  u16x8 o0, o1;
#pragma unroll
  for (int i = 0; i < 8; ++i) o0[i] = f2bf(ts[c0 + i][r]);
#pragma unroll
  for (int i = 0; i < 8; ++i) o1[i] = f2bf(ts[c0 + 8 + i][r]);
  unsigned short* dst = wT + (size_t)(mat * 256 + tc + r) * 256 + tr + c0;
  *(u16x8*)dst = o0;
  *(u16x8*)(dst + 8) = o1;
}

// ============ global_load_lds double-buffered GEMM: C[M,N] = A16[M,256] @ BT[N,256]^T ======
// 512 thr / 8 waves, tile 128x128, BK=64 (4 kt). A,B bf16. Staging = 4 global_load_lds
// insts/wave/kt (1KB each), pre-swizzled SOURCE + linear LDS dest (XOR k8^row&7).
// Double-buffered LDS (64KB). Counted s_waitcnt vmcnt(4): next tile's DMA stays in flight
// across the whole compute phase; raw s_barrier (no drain).
template <typename OutT>
__global__ __launch_bounds__(512, 4) void gemm_g2l(const unsigned short* __restrict__ A,
                                                   const unsigned short* __restrict__ BT,
                                                   OutT* __restrict__ C,
                                                   int M, int CP, int ldc) {
  __shared__ unsigned short lds[4][128 * 64];   // [buf*2 + (0=A,1=B)][row*64 + k]
  int tid = threadIdx.x;
  int nb = gridDim.x, bid = blockIdx.x;
  int L = bid;
  if ((nb & 7) == 0) L = (bid & 7) * (nb >> 3) + (bid >> 3);   // XCD-chunked swizzle
  int rp = L / CP, cp = L - rp * CP;

  int wid = tid >> 6, lane = tid & 63, l15 = lane & 15, slot = lane >> 4;
  int wr = (wid >> 2) * 64, wc = (wid & 3) * 32;   // wave tile 64x32

  // staging source: lane (r8, k8); global col = kt*64 + (k8 ^ r8)*8 (inverse swizzle);
  // LDS linear dest slot = row*128B + k8*16B  ->  LDS[row][k8] holds k-group (k8 ^ (row&7))
  int r8 = lane >> 3, k8 = lane & 7;
  int colsw = (k8 ^ r8) << 3;
  const unsigned short* ga0 = A  + (size_t)(rp * 128 + wid * 16 + r8) * 256 + colsw;
  const unsigned short* gb0 = BT + (size_t)(cp * 128 + wid * 16 + r8) * 256 + colsw;

#define STAGE(b, kt) do { \
    const unsigned short* ga = ga0 + (kt) * 64; \
    const unsigned short* gb = gb0 + (kt) * 64; \
    gl_lds16(ga,           &lds[(b)*2    ][(wid*16    ) * 64]); \
    gl_lds16(ga + 8*256,   &lds[(b)*2    ][(wid*16 + 8) * 64]); \
    gl_lds16(gb,           &lds[(b)*2 + 1][(wid*16    ) * 64]); \
    gl_lds16(gb + 8*256,   &lds[(b)*2 + 1][(wid*16 + 8) * 64]); \
  } while (0)

  f32x4 acc[4][2] = {};
  STAGE(0, 0);

#pragma unroll
  for (int kt = 0; kt < 4; ++kt) {
    int b = kt & 1;
    if (kt < 3) STAGE(b ^ 1, kt + 1);   // in flight across this kt's compute
    if (kt < 3) asm volatile("s_waitcnt vmcnt(4)" ::: "memory");
    else        asm volatile("s_waitcnt vmcnt(0)" ::: "memory");
    __builtin_amdgcn_s_barrier();
    asm volatile("" ::: "memory");
    const unsigned short* As = lds[b*2];
    const unsigned short* Bs = lds[b*2 + 1];
#pragma unroll
    for (int kf = 0; kf < 2; ++kf) {
      short8 afr[4], bfr[2];
      int kg = kf * 4 + slot;
      int sx = kg ^ (l15 & 7);
#pragma unroll
      for (int mm = 0; mm < 4; ++mm) {
        int row = wr + mm * 16 + l15;
        afr[mm] = *(const short8*)&As[row * 64 + (sx << 3)];
      }
#pragma unroll
      for (int nn = 0; nn < 2; ++nn) {
        int col = wc + nn * 16 + l15;
        bfr[nn] = *(const short8*)&Bs[col * 64 + (sx << 3)];
      }
#pragma unroll
      for (int mm = 0; mm < 4; ++mm)
#pragma unroll
        for (int nn = 0; nn < 2; ++nn)
          acc[mm][nn] = __builtin_amdgcn_mfma_f32_16x16x32_bf16(afr[mm], bfr[nn], acc[mm][nn], 0, 0, 0);
    }
    asm volatile("" ::: "memory");
    __builtin_amdgcn_s_barrier();
    asm volatile("" ::: "memory");
  }
#undef STAGE

  // ---- epilogue: C/D layout col=lane&15, row=(lane>>4)*4+j ----
#pragma unroll
  for (int mm = 0; mm < 4; ++mm) {
#pragma unroll
    for (int nn = 0; nn < 2; ++nn) {
      int grow0 = rp * 128 + wr + mm * 16 + slot * 4;
      int gcol  = cp * 128 + wc + nn * 16 + l15;
#pragma unroll
      for (int j = 0; j < 4; ++j) {
        size_t o = (size_t)(grow0 + j) * ldc + gcol;
        if constexpr (__is_same(OutT, float)) C[o] = acc[mm][nn][j];
        else                                  C[o] = __float2bfloat16(acc[mm][nn][j]);
      }
    }
  }
}

// ---------------- masked cross-attention: one wave per cell, online softmax ---------------
__global__ __launch_bounds__(256) void attn_kernel(
    const float* __restrict__ lat,          // [1024][768]  q|k|v
    const __hip_bfloat16* __restrict__ kv,  // [m*n][512]   k|v
    const int* __restrict__ pts2,           // [MS][16]: w0=eff, w1..15 sorted pt indices
    __hip_bfloat16* __restrict__ attn_out, int n) {
  const float scale = 0.17677669529663687f;  // 1/sqrt(32)
  int wid = threadIdx.x >> 6;
  int lane = threadIdx.x & 63;
  int cellg = blockIdx.x * 4 + wid;
  int b = cellg >> 13;                 // S_=8192, cells per batch
  int c = cellg & (SP_ - 1);           // spatial index -> latent row
  int d0 = lane << 2;                  // 4 dims per lane

  const int* pp = pts2 + (size_t)cellg * P_;
  int4 h0 = *(const int4*)pp;          // eff, pt0, pt1, pt2 (broadcast load)
  int eff = h0.x;

  const float* latc = lat + c * 768 + d0;
  float4 q  = *(const float4*)latc;
  float4 kl = *(const float4*)(latc + 256);
  float4 vl = *(const float4*)(latc + 512);

  // grid-token logit -> init online-softmax state
  float part = q.x*kl.x + q.y*kl.y + q.z*kl.z + q.w*kl.w;
  part += __shfl_xor(part, 1);
  part += __shfl_xor(part, 2);
  part += __shfl_xor(part, 4);         // head-local (8 lanes = 32 dims)
  float mx = part * scale;
  float ssum = 1.f;
  float4 acc = vl;

  const unsigned short* kvp = (const unsigned short*)kv;
  size_t bbase = (size_t)b * n;

  int pt[4]; pt[0] = h0.y; pt[1] = h0.z; pt[2] = h0.w; pt[3] = 0;
  int done = 0, cap = 3;
  while (done < eff) {
    int np = eff - done; if (np > cap) np = cap;
    ushort4 kr[4], vr[4];
#pragma unroll
    for (int i = 0; i < 4; ++i) if (i < np) {
      size_t row = (bbase + (size_t)pt[i]) * 512;
      kr[i] = *(const ushort4*)(kvp + row + d0);
      vr[i] = *(const ushort4*)(kvp + row + 256 + d0);
    }
#pragma unroll
    for (int i = 0; i < 4; ++i) if (i < np) {
      float p = q.x*bf2f(kr[i].x) + q.y*bf2f(kr[i].y) + q.z*bf2f(kr[i].z) + q.w*bf2f(kr[i].w);
      p += __shfl_xor(p, 1);
      p += __shfl_xor(p, 2);
      p += __shfl_xor(p, 4);
      p *= scale;
      float m2 = fmaxf(mx, p);
      float corr = __expf(mx - m2);
      float e = __expf(p - m2);
      ssum = ssum * corr + e;
      acc.x = acc.x * corr + e * bf2f(vr[i].x);
      acc.y = acc.y * corr + e * bf2f(vr[i].y);
      acc.z = acc.z * corr + e * bf2f(vr[i].z);
      acc.w = acc.w * corr + e * bf2f(vr[i].w);
      mx = m2;
    }
    done += np;
    cap = 4;
    if (done < eff) {
      int4 h = *(const int4*)(pp + 1 + done);   // done in {3,7,11} -> aligned
      pt[0] = h.x; pt[1] = h.y; pt[2] = h.z; pt[3] = h.w;
    }
  }
  float inv = 1.f / ssum;
  ushort4 o;
  o.x = f2bf(acc.x * inv); o.y = f2bf(acc.y * inv);
  o.z = f2bf(acc.z * inv); o.w = f2bf(acc.w * inv);
  *(ushort4*)((unsigned short*)attn_out + (size_t)cellg * E_ + d0) = o;
}

// -------------------------------------------------------------------------------------------
extern "C" void kernel_launch(void* const* d_in, const int* in_sizes, int n_in,
                              void* d_out, int out_size, void* d_ws, size_t ws_size,
                              hipStream_t stream) {
  const float* x       = (const float*)d_in[0];
  const float* z       = (const float*)d_in[1];
  const float* tg      = (const float*)d_in[2];
  const float* latents = (const float*)d_in[3];
  const float* grid    = (const float*)d_in[4];
  const float* Wq      = (const float*)d_in[5];
  const float* Wk      = (const float*)d_in[6];
  const float* Wv      = (const float*)d_in[7];
  const float* Wo      = (const float*)d_in[8];

  int m = in_sizes[2] / T_;              // 4
  int n = in_sizes[1] / (m * E_);        // 16384
  int MS = m * S_;                       // 32768
  float* out = (float*)d_out;
  int tot_xg = m * T_ * SP_;             // 32768 grid sites

  // ---- workspace carve (256B aligned) ----
  char* w = (char*)d_ws;
  auto alloc = [&](size_t bytes) { char* p = w; w += (bytes + 255) & ~(size_t)255; return p; };
  float* stats      = (float*)alloc((size_t)m * 8 * 4);
  int*   counts     = (int*)  alloc((size_t)MS * 4);
  int*   cell_raw   = (int*)  alloc((size_t)MS * P_ * 4);
  int*   pts2       = (int*)  alloc((size_t)MS * P_ * 4);
  unsigned short* wT    = (unsigned short*)alloc((size_t)1024 * 256 * 2);
  unsigned short* lat16 = (unsigned short*)alloc((size_t)SP_ * E_ * 2);
  float* lat        = (float*)alloc((size_t)SP_ * 768 * 4);
  __hip_bfloat16* kv       = (__hip_bfloat16*)alloc((size_t)m * n * 512 * 2);
  __hip_bfloat16* attn_out = (__hip_bfloat16*)alloc((size_t)MS * E_ * 2);

  // z16 (m*n*256 bf16 = 32MB) lives in d_out's z_grid region (exact byte fit);
  // it is dead before the Wo GEMM finally writes z_grid there.
  unsigned short* z16 = (unsigned short*)(out + (size_t)tot_xg * 3);

  (void)hipMemsetAsync(counts, 0, (size_t)MS * 4, stream);
  stats_kernel<<<1, 64, 0, stream>>>(tg, grid, stats, m);

  xgrid_kernel<<<(tot_xg + 255)/256, 256, 0, stream>>>(tg, grid, out, tot_xg);

  assign_kernel<<<(m*n + 255)/256, 256, 0, stream>>>(x, stats, counts, cell_raw, m, n);
  finalize_kernel<<<(MS + 255)/256, 256, 0, stream>>>(counts, cell_raw, pts2, MS);

  // weights: transpose + convert to bf16  [Wq|Wk|Wv|Wo]^T
  wtrans_kernel<<<64, 256, 0, stream>>>(Wq, Wk, Wv, Wo, wT);

  // bf16 conversions: z -> z16 (into d_out scratch), latents -> lat16
  cvt_kernel<<<2048, 256, 0, stream>>>(z, z16, m * n * E_ / 8);
  cvt_kernel<<<128, 256, 0, stream>>>(latents, lat16, SP_ * E_ / 8);

  // latent projections fused: lat[1024,768] = latents @ [Wq|Wk|Wv]   (8 rp x 6 cp = 48)
  gemm_g2l<float><<<48, 512, 0, stream>>>(lat16, wT, lat, SP_, 6, 768);

  // point projections fused: kv[m*n,512] = z16 @ [Wk|Wv]   (512 rp x 4 cp = 2048)
  gemm_g2l<__hip_bfloat16><<<2048, 512, 0, stream>>>(
      z16, wT + (size_t)256*256, (__hip_bfloat16*)kv, m*n, 4, 512);

  // attention: one wave per cell
  attn_kernel<<<MS/4, 256, 0, stream>>>(lat, kv, pts2, attn_out, n);

  // output projection -> z_grid (overwrites z16 scratch)   (256 rp x 2 cp = 512)
  gemm_g2l<float><<<512, 512, 0, stream>>>(
      (const unsigned short*)attn_out, wT + (size_t)768*256, out + (size_t)tot_xg * 3, MS, 2, 256);
}

// Round 11
// 104.162 us; speedup vs baseline: 1.1117x; 1.1117x over previous
//
#include <hip/hip_runtime.h>
#include <hip/hip_bf16.h>

#define T_ 8
#define N0_ 32
#define N1_ 32
#define SP_ (N0_*N1_)   /* 1024 spatial cells */
#define S_ (T_*SP_)     /* 8192 space-time cells */
#define E_ 256
#define P_ 16
#define NH_ 8
#define HD_ 32
#define ZB_ 2048        /* z-cvt blocks in mega_prep */

typedef __attribute__((ext_vector_type(8))) short short8;
typedef __attribute__((ext_vector_type(4))) float f32x4;
typedef __attribute__((ext_vector_type(8))) unsigned short u16x8;

__device__ __forceinline__ unsigned short f2bf(float f) {
  __hip_bfloat16 h = __float2bfloat16(f);
  return *reinterpret_cast<unsigned short*>(&h);
}
__device__ __forceinline__ float bf2f(unsigned short u) {
  return __uint_as_float((unsigned)u << 16);
}

// async global->LDS, 16B per lane; dst = wave-uniform base + lane*16
__device__ __forceinline__ void gl_lds16(const unsigned short* g, unsigned short* l) {
  __builtin_amdgcn_global_load_lds(
      (const __attribute__((address_space(1))) unsigned int*)(g),
      (__attribute__((address_space(3))) unsigned int*)(l), 16, 0, 0);
}

// ============ mega_prep: z cvt | wtrans | lat cvt | zero counts (block-range dispatch) =====
__global__ __launch_bounds__(256) void mega_prep(const float* __restrict__ z,
                                                 unsigned short* __restrict__ z16,
                                                 const float* __restrict__ Wq,
                                                 const float* __restrict__ Wk,
                                                 const float* __restrict__ Wv,
                                                 const float* __restrict__ Wo,
                                                 unsigned short* __restrict__ wT,
                                                 const float* __restrict__ latents,
                                                 unsigned short* __restrict__ lat16,
                                                 int* __restrict__ counts,
                                                 int zn8, int MS) {
  __shared__ float ts[64][65];
  int bid = blockIdx.x;
  int t = threadIdx.x;
  if (bid < ZB_) {
    // ---- z fp32 -> bf16 ----
    int stride = ZB_ * 256;
    for (int i = bid * 256 + t; i < zn8; i += stride) {
      float4 a = *(const float4*)(z + (size_t)i * 8);
      float4 b = *(const float4*)(z + (size_t)i * 8 + 4);
      u16x8 o;
      o[0]=f2bf(a.x); o[1]=f2bf(a.y); o[2]=f2bf(a.z); o[3]=f2bf(a.w);
      o[4]=f2bf(b.x); o[5]=f2bf(b.y); o[6]=f2bf(b.z); o[7]=f2bf(b.w);
      *(u16x8*)(z16 + (size_t)i * 8) = o;
    }
  } else if (bid < ZB_ + 64) {
    // ---- weight transpose+convert: wT[1024][256] = [Wq|Wk|Wv|Wo]^T ----
    int wb = bid - ZB_;
    int mat = wb >> 4;
    int tile = wb & 15;
    int tr = (tile >> 2) * 64;
    int tc = (tile & 3) * 64;
    const float* W = mat == 0 ? Wq : mat == 1 ? Wk : mat == 2 ? Wv : Wo;
    int r = t >> 2, c0 = (t & 3) * 16;
#pragma unroll
    for (int i = 0; i < 4; ++i) {
      float4 v = *(const float4*)&W[(size_t)(tr + r) * 256 + tc + c0 + i*4];
      ts[r][c0 + i*4 + 0] = v.x; ts[r][c0 + i*4 + 1] = v.y;
      ts[r][c0 + i*4 + 2] = v.z; ts[r][c0 + i*4 + 3] = v.w;
    }
    __syncthreads();
    u16x8 o0, o1;
#pragma unroll
    for (int i = 0; i < 8; ++i) o0[i] = f2bf(ts[c0 + i][r]);
#pragma unroll
    for (int i = 0; i < 8; ++i) o1[i] = f2bf(ts[c0 + 8 + i][r]);
    unsigned short* dst = wT + (size_t)(mat * 256 + tc + r) * 256 + tr + c0;
    *(u16x8*)dst = o0;
    *(u16x8*)(dst + 8) = o1;
  } else if (bid < ZB_ + 80) {
    // ---- latents fp32 -> bf16 (1024*256/8 = 32768 groups over 16 blocks) ----
    int i0 = (bid - ZB_ - 64) * 256 + t;
    for (int i = i0; i < SP_ * E_ / 8; i += 16 * 256) {
      float4 a = *(const float4*)(latents + (size_t)i * 8);
      float4 b = *(const float4*)(latents + (size_t)i * 8 + 4);
      u16x8 o;
      o[0]=f2bf(a.x); o[1]=f2bf(a.y); o[2]=f2bf(a.z); o[3]=f2bf(a.w);
      o[4]=f2bf(b.x); o[5]=f2bf(b.y); o[6]=f2bf(b.z); o[7]=f2bf(b.w);
      *(u16x8*)(lat16 + (size_t)i * 8) = o;
    }
  } else {
    // ---- zero counts (MS ints over 16 blocks) ----
    int i0 = (bid - ZB_ - 80) * 256 + t;
    for (int i = i0; i < MS / 4; i += 16 * 256)
      *(int4*)(counts + i * 4) = make_int4(0, 0, 0, 0);
  }
}

// ============ assign2: per-block stats (identical fp32 ops) + x_grid + point assign ========
__global__ __launch_bounds__(256) void assign2_kernel(const float* __restrict__ x,
                                                      const float* __restrict__ tg,
                                                      const float* __restrict__ grid,
                                                      float* __restrict__ out,
                                                      int* __restrict__ counts,
                                                      int* __restrict__ cell_raw,
                                                      int m, int n, int tot_xg) {
  __shared__ float st[4][6];
  int tid = threadIdx.x;
  if (tid < 64) {
    float mn0 = 1e30f, mx0 = -1e30f, mn1 = 1e30f, mx1 = -1e30f;
    for (int i = tid; i < SP_; i += 64) {
      float g0 = grid[i*2], g1 = grid[i*2+1];
      mn0 = fminf(mn0, g0); mx0 = fmaxf(mx0, g0);
      mn1 = fminf(mn1, g1); mx1 = fmaxf(mx1, g1);
    }
    for (int msk = 32; msk; msk >>= 1) {
      mn0 = fminf(mn0, __shfl_xor(mn0, msk));
      mx0 = fmaxf(mx0, __shfl_xor(mx0, msk));
      mn1 = fminf(mn1, __shfl_xor(mn1, msk));
      mx1 = fmaxf(mx1, __shfl_xor(mx1, msk));
    }
    if (tid == 0) {
      for (int b = 0; b < m; ++b) {
        float tmn = 1e30f, tmx = -1e30f;
        for (int tt = 0; tt < T_; ++tt) {
          float v = tg[b*T_ + tt];
          tmn = fminf(tmn, v); tmx = fmaxf(tmx, v);
        }
        st[b][0] = tmn; st[b][1] = mn0; st[b][2] = mn1;
        st[b][3] = (tmx - tmn) / (float)(T_ - 1);
        st[b][4] = (mx0 - mn0) / (float)(N0_ - 1);
        st[b][5] = (mx1 - mn1) / (float)(N1_ - 1);
      }
    }
  }
  __syncthreads();
  int idx = blockIdx.x * 256 + tid;
  if (idx < tot_xg) {                       // x_grid
    int sp = idx & (SP_ - 1);
    int bt = idx >> 10;
    out[idx*3 + 0] = tg[bt];
    out[idx*3 + 1] = grid[sp*2 + 0];
    out[idx*3 + 2] = grid[sp*2 + 1];
  }
  if (idx < m*n) {                          // assign
    int b = idx / n;
    int j = idx - b*n;
    const float* s = st[b];
    float xt = x[(size_t)idx*3 + 0], x0 = x[(size_t)idx*3 + 1], x1 = x[(size_t)idx*3 + 2];
    float m0 = floorf((xt - s[0] + s[3]*0.5f) / s[3]);
    float m1 = floorf((x0 - s[1] + s[4]*0.5f) / s[4]);
    float m2 = floorf((x1 - s[2] + s[5]*0.5f) / s[5]);
    m0 = fminf(fmaxf(m0, 0.f), (float)(T_ - 1));
    m1 = fminf(fmaxf(m1, 0.f), (float)(N0_ - 1));
    m2 = fminf(fmaxf(m2, 0.f), (float)(N1_ - 1));
    int sc = (int)m0 * SP_ + (int)m1 * N1_ + (int)m2;
    int cg = b * S_ + sc;
    int old = atomicAdd(&counts[cg], 1);
    if (old < P_) cell_raw[(size_t)cg * P_ + old] = j;
  }
}

// ------- per-cell: sort indices (determinism + exact first-15 drop), pack eff+pts ---------
__global__ void finalize_kernel(const int* __restrict__ counts, int* __restrict__ cell_raw,
                                int* __restrict__ pts2, int total) {
  int cg = blockIdx.x * blockDim.x + threadIdx.x;
  if (cg >= total) return;
  int cnt = counts[cg];
  int stored = cnt < P_ ? cnt : P_;
  int eff = cnt < (P_ - 1) ? cnt : (P_ - 1);
  int* p = cell_raw + (size_t)cg * P_;
  for (int i = 1; i < stored; ++i) {   // insertion sort ascending (original index order)
    int key = p[i]; int j = i - 1;
    while (j >= 0 && p[j] > key) { p[j+1] = p[j]; --j; }
    p[j+1] = key;
  }
  int* o = pts2 + (size_t)cg * P_;
  o[0] = eff;
  for (int i = 0; i < eff; ++i) o[1 + i] = p[i];
}

// ============ global_load_lds double-buffered GEMM: C[M,N] = A16[M,256] @ BT[N,256]^T ======
// 512 thr / 8 waves, tile 128x128, BK=64 (4 kt). Staging = 4 global_load_lds insts/wave/kt,
// pre-swizzled SOURCE + linear LDS dest. Counted s_waitcnt vmcnt(4); raw s_barrier.
template <typename OutT>
__global__ __launch_bounds__(512, 4) void gemm_g2l(const unsigned short* __restrict__ A,
                                                   const unsigned short* __restrict__ BT,
                                                   OutT* __restrict__ C,
                                                   int M, int CP, int ldc) {
  __shared__ unsigned short lds[4][128 * 64];   // [buf*2 + (0=A,1=B)][row*64 + k]
  int tid = threadIdx.x;
  int nb = gridDim.x, bid = blockIdx.x;
  int L = bid;
  if ((nb & 7) == 0) L = (bid & 7) * (nb >> 3) + (bid >> 3);   // XCD-chunked swizzle
  int rp = L / CP, cp = L - rp * CP;

  int wid = tid >> 6, lane = tid & 63, l15 = lane & 15, slot = lane >> 4;
  int wr = (wid >> 2) * 64, wc = (wid & 3) * 32;   // wave tile 64x32

  int r8 = lane >> 3, k8 = lane & 7;
  int colsw = (k8 ^ r8) << 3;
  const unsigned short* ga0 = A  + (size_t)(rp * 128 + wid * 16 + r8) * 256 + colsw;
  const unsigned short* gb0 = BT + (size_t)(cp * 128 + wid * 16 + r8) * 256 + colsw;

#define STAGE(b, kt) do { \
    const unsigned short* ga = ga0 + (kt) * 64; \
    const unsigned short* gb = gb0 + (kt) * 64; \
    gl_lds16(ga,           &lds[(b)*2    ][(wid*16    ) * 64]); \
    gl_lds16(ga + 8*256,   &lds[(b)*2    ][(wid*16 + 8) * 64]); \
    gl_lds16(gb,           &lds[(b)*2 + 1][(wid*16    ) * 64]); \
    gl_lds16(gb + 8*256,   &lds[(b)*2 + 1][(wid*16 + 8) * 64]); \
  } while (0)

  f32x4 acc[4][2] = {};
  STAGE(0, 0);

#pragma unroll
  for (int kt = 0; kt < 4; ++kt) {
    int b = kt & 1;
    if (kt < 3) STAGE(b ^ 1, kt + 1);   // in flight across this kt's compute
    if (kt < 3) asm volatile("s_waitcnt vmcnt(4)" ::: "memory");
    else        asm volatile("s_waitcnt vmcnt(0)" ::: "memory");
    __builtin_amdgcn_s_barrier();
    asm volatile("" ::: "memory");
    const unsigned short* As = lds[b*2];
    const unsigned short* Bs = lds[b*2 + 1];
#pragma unroll
    for (int kf = 0; kf < 2; ++kf) {
      short8 afr[4], bfr[2];
      int kg = kf * 4 + slot;
      int sx = kg ^ (l15 & 7);
#pragma unroll
      for (int mm = 0; mm < 4; ++mm) {
        int row = wr + mm * 16 + l15;
        afr[mm] = *(const short8*)&As[row * 64 + (sx << 3)];
      }
#pragma unroll
      for (int nn = 0; nn < 2; ++nn) {
        int col = wc + nn * 16 + l15;
        bfr[nn] = *(const short8*)&Bs[col * 64 + (sx << 3)];
      }
#pragma unroll
      for (int mm = 0; mm < 4; ++mm)
#pragma unroll
        for (int nn = 0; nn < 2; ++nn)
          acc[mm][nn] = __builtin_amdgcn_mfma_f32_16x16x32_bf16(afr[mm], bfr[nn], acc[mm][nn], 0, 0, 0);
    }
    asm volatile("" ::: "memory");
    __builtin_amdgcn_s_barrier();
    asm volatile("" ::: "memory");
  }
#undef STAGE

  // ---- epilogue: C/D layout col=lane&15, row=(lane>>4)*4+j ----
#pragma unroll
  for (int mm = 0; mm < 4; ++mm) {
#pragma unroll
    for (int nn = 0; nn < 2; ++nn) {
      int grow0 = rp * 128 + wr + mm * 16 + slot * 4;
      int gcol  = cp * 128 + wc + nn * 16 + l15;
#pragma unroll
      for (int j = 0; j < 4; ++j) {
        size_t o = (size_t)(grow0 + j) * ldc + gcol;
        if constexpr (__is_same(OutT, float)) C[o] = acc[mm][nn][j];
        else                                  C[o] = __float2bfloat16(acc[mm][nn][j]);
      }
    }
  }
}

// ---------------- masked cross-attention: one wave per cell, online softmax ---------------
__global__ __launch_bounds__(256) void attn_kernel(
    const float* __restrict__ lat,          // [1024][768]  q|k|v
    const __hip_bfloat16* __restrict__ kv,  // [m*n][512]   k|v
    const int* __restrict__ pts2,           // [MS][16]: w0=eff, w1..15 sorted pt indices
    __hip_bfloat16* __restrict__ attn_out, int n) {
  const float scale = 0.17677669529663687f;  // 1/sqrt(32)
  int wid = threadIdx.x >> 6;
  int lane = threadIdx.x & 63;
  int cellg = blockIdx.x * 4 + wid;
  int b = cellg >> 13;                 // S_=8192, cells per batch
  int c = cellg & (SP_ - 1);           // spatial index -> latent row
  int d0 = lane << 2;                  // 4 dims per lane

  const int* pp = pts2 + (size_t)cellg * P_;
  int4 h0 = *(const int4*)pp;          // eff, pt0, pt1, pt2 (broadcast load)
  int eff = h0.x;

  const float* latc = lat + c * 768 + d0;
  float4 q  = *(const float4*)latc;
  float4 kl = *(const float4*)(latc + 256);
  float4 vl = *(const float4*)(latc + 512);

  // grid-token logit -> init online-softmax state
  float part = q.x*kl.x + q.y*kl.y + q.z*kl.z + q.w*kl.w;
  part += __shfl_xor(part, 1);
  part += __shfl_xor(part, 2);
  part += __shfl_xor(part, 4);         // head-local (8 lanes = 32 dims)
  float mx = part * scale;
  float ssum = 1.f;
  float4 acc = vl;

  const unsigned short* kvp = (const unsigned short*)kv;
  size_t bbase = (size_t)b * n;

  int pt[4]; pt[0] = h0.y; pt[1] = h0.z; pt[2] = h0.w; pt[3] = 0;
  int done = 0, cap = 3;
  while (done < eff) {
    int np = eff - done; if (np > cap) np = cap;
    ushort4 kr[4], vr[4];
#pragma unroll
    for (int i = 0; i < 4; ++i) if (i < np) {
      size_t row = (bbase + (size_t)pt[i]) * 512;
      kr[i] = *(const ushort4*)(kvp + row + d0);
      vr[i] = *(const ushort4*)(kvp + row + 256 + d0);
    }
#pragma unroll
    for (int i = 0; i < 4; ++i) if (i < np) {
      float p = q.x*bf2f(kr[i].x) + q.y*bf2f(kr[i].y) + q.z*bf2f(kr[i].z) + q.w*bf2f(kr[i].w);
      p += __shfl_xor(p, 1);
      p += __shfl_xor(p, 2);
      p += __shfl_xor(p, 4);
      p *= scale;
      float m2 = fmaxf(mx, p);
      float corr = __expf(mx - m2);
      float e = __expf(p - m2);
      ssum = ssum * corr + e;
      acc.x = acc.x * corr + e * bf2f(vr[i].x);
      acc.y = acc.y * corr + e * bf2f(vr[i].y);
      acc.z = acc.z * corr + e * bf2f(vr[i].z);
      acc.w = acc.w * corr + e * bf2f(vr[i].w);
      mx = m2;
    }
    done += np;
    cap = 4;
    if (done < eff) {
      int4 h = *(const int4*)(pp + 1 + done);   // done in {3,7,11} -> aligned
      pt[0] = h.x; pt[1] = h.y; pt[2] = h.z; pt[3] = h.w;
    }
  }
  float inv = 1.f / ssum;
  ushort4 o;
  o.x = f2bf(acc.x * inv); o.y = f2bf(acc.y * inv);
  o.z = f2bf(acc.z * inv); o.w = f2bf(acc.w * inv);
  *(ushort4*)((unsigned short*)attn_out + (size_t)cellg * E_ + d0) = o;
}

// -------------------------------------------------------------------------------------------
extern "C" void kernel_launch(void* const* d_in, const int* in_sizes, int n_in,
                              void* d_out, int out_size, void* d_ws, size_t ws_size,
                              hipStream_t stream) {
  const float* x       = (const float*)d_in[0];
  const float* z       = (const float*)d_in[1];
  const float* tg      = (const float*)d_in[2];
  const float* latents = (const float*)d_in[3];
  const float* grid    = (const float*)d_in[4];
  const float* Wq      = (const float*)d_in[5];
  const float* Wk      = (const float*)d_in[6];
  const float* Wv      = (const float*)d_in[7];
  const float* Wo      = (const float*)d_in[8];

  int m = in_sizes[2] / T_;              // 4
  int n = in_sizes[1] / (m * E_);        // 16384
  int MS = m * S_;                       // 32768
  float* out = (float*)d_out;
  int tot_xg = m * T_ * SP_;             // 32768 grid sites

  // ---- workspace carve (256B aligned) ----
  char* w = (char*)d_ws;
  auto alloc = [&](size_t bytes) { char* p = w; w += (bytes + 255) & ~(size_t)255; return p; };
  int*   counts     = (int*)  alloc((size_t)MS * 4);
  int*   cell_raw   = (int*)  alloc((size_t)MS * P_ * 4);
  int*   pts2       = (int*)  alloc((size_t)MS * P_ * 4);
  unsigned short* wT    = (unsigned short*)alloc((size_t)1024 * 256 * 2);
  unsigned short* lat16 = (unsigned short*)alloc((size_t)SP_ * E_ * 2);
  float* lat        = (float*)alloc((size_t)SP_ * 768 * 4);
  __hip_bfloat16* kv       = (__hip_bfloat16*)alloc((size_t)m * n * 512 * 2);
  __hip_bfloat16* attn_out = (__hip_bfloat16*)alloc((size_t)MS * E_ * 2);

  // z16 (m*n*256 bf16 = 32MB) lives in d_out's z_grid region (exact byte fit);
  // dead before the Wo GEMM writes z_grid there.
  unsigned short* z16 = (unsigned short*)(out + (size_t)tot_xg * 3);

  // 1) mega_prep: z cvt | wtrans | lat cvt | zero counts
  mega_prep<<<ZB_ + 96, 256, 0, stream>>>(z, z16, Wq, Wk, Wv, Wo, wT, latents, lat16,
                                          counts, m * n * E_ / 8, MS);

  // 2) stats + x_grid + assign
  assign2_kernel<<<(m*n + 255)/256, 256, 0, stream>>>(x, tg, grid, out, counts, cell_raw,
                                                      m, n, tot_xg);

  // 3) finalize (sort + pack)
  finalize_kernel<<<(MS + 255)/256, 256, 0, stream>>>(counts, cell_raw, pts2, MS);

  // 4) latent projections fused: lat[1024,768] = latents @ [Wq|Wk|Wv]   (8 rp x 6 cp)
  gemm_g2l<float><<<48, 512, 0, stream>>>(lat16, wT, lat, SP_, 6, 768);

  // 5) point projections fused: kv[m*n,512] = z16 @ [Wk|Wv]   (512 rp x 4 cp)
  gemm_g2l<__hip_bfloat16><<<2048, 512, 0, stream>>>(
      z16, wT + (size_t)256*256, (__hip_bfloat16*)kv, m*n, 4, 512);

  // 6) attention: one wave per cell
  attn_kernel<<<MS/4, 256, 0, stream>>>(lat, kv, pts2, attn_out, n);

  // 7) output projection -> z_grid (overwrites z16 scratch)   (256 rp x 2 cp)
  gemm_g2l<float><<<512, 512, 0, stream>>>(
      (const unsigned short*)attn_out, wT + (size_t)768*256, out + (size_t)tot_xg * 3, MS, 2, 256);
}

// Round 12
// 100.812 us; speedup vs baseline: 1.1487x; 1.0332x over previous
//
#include <hip/hip_runtime.h>
#include <hip/hip_bf16.h>

#define T_ 8
#define N0_ 32
#define N1_ 32
#define SP_ (N0_*N1_)   /* 1024 spatial cells */
#define S_ (T_*SP_)     /* 8192 space-time cells */
#define E_ 256
#define P_ 16
#define NH_ 8
#define HD_ 32

typedef __attribute__((ext_vector_type(8))) short short8;
typedef __attribute__((ext_vector_type(4))) float f32x4;
typedef __attribute__((ext_vector_type(8))) unsigned short u16x8;

__device__ __forceinline__ unsigned short f2bf(float f) {
  __hip_bfloat16 h = __float2bfloat16(f);
  return *reinterpret_cast<unsigned short*>(&h);
}
__device__ __forceinline__ float bf2f(unsigned short u) {
  return __uint_as_float((unsigned)u << 16);
}

// async global->LDS, 16B per lane; dst = wave-uniform base + lane*16
__device__ __forceinline__ void gl_lds16(const void* g, void* l) {
  __builtin_amdgcn_global_load_lds(
      (const __attribute__((address_space(1))) unsigned int*)(g),
      (__attribute__((address_space(3))) unsigned int*)(l), 16, 0, 0);
}

// ============ prep_assign: [0..256) stats+x_grid+assign | [256..320) wtrans ================
__global__ __launch_bounds__(256) void prep_assign(const float* __restrict__ x,
                                                   const float* __restrict__ tg,
                                                   const float* __restrict__ grid,
                                                   float* __restrict__ out,
                                                   int* __restrict__ counts,
                                                   int* __restrict__ cell_raw,
                                                   const float* __restrict__ Wq,
                                                   const float* __restrict__ Wk,
                                                   const float* __restrict__ Wv,
                                                   const float* __restrict__ Wo,
                                                   unsigned short* __restrict__ wT,
                                                   int m, int n, int tot_xg) {
  __shared__ float ts[64][65];
  int bid = blockIdx.x;
  int tid = threadIdx.x;
  if (bid >= 256) {
    // ---- weight transpose+convert: wT[1024][256] = [Wq|Wk|Wv|Wo]^T ----
    int wb = bid - 256;
    int mat = wb >> 4;
    int tile = wb & 15;
    int tr = (tile >> 2) * 64;
    int tc = (tile & 3) * 64;
    const float* W = mat == 0 ? Wq : mat == 1 ? Wk : mat == 2 ? Wv : Wo;
    int r = tid >> 2, c0 = (tid & 3) * 16;
#pragma unroll
    for (int i = 0; i < 4; ++i) {
      float4 v = *(const float4*)&W[(size_t)(tr + r) * 256 + tc + c0 + i*4];
      ts[r][c0 + i*4 + 0] = v.x; ts[r][c0 + i*4 + 1] = v.y;
      ts[r][c0 + i*4 + 2] = v.z; ts[r][c0 + i*4 + 3] = v.w;
    }
    __syncthreads();
    u16x8 o0, o1;
#pragma unroll
    for (int i = 0; i < 8; ++i) o0[i] = f2bf(ts[c0 + i][r]);
#pragma unroll
    for (int i = 0; i < 8; ++i) o1[i] = f2bf(ts[c0 + 8 + i][r]);
    unsigned short* dst = wT + (size_t)(mat * 256 + tc + r) * 256 + tr + c0;
    *(u16x8*)dst = o0;
    *(u16x8*)(dst + 8) = o1;
    return;
  }
  // ---- stats (per-block, byte-identical fp32 op order) + x_grid + assign ----
  __shared__ float st[4][6];
  if (tid < 64) {
    float mn0 = 1e30f, mx0 = -1e30f, mn1 = 1e30f, mx1 = -1e30f;
    for (int i = tid; i < SP_; i += 64) {
      float g0 = grid[i*2], g1 = grid[i*2+1];
      mn0 = fminf(mn0, g0); mx0 = fmaxf(mx0, g0);
      mn1 = fminf(mn1, g1); mx1 = fmaxf(mx1, g1);
    }
    for (int msk = 32; msk; msk >>= 1) {
      mn0 = fminf(mn0, __shfl_xor(mn0, msk));
      mx0 = fmaxf(mx0, __shfl_xor(mx0, msk));
      mn1 = fminf(mn1, __shfl_xor(mn1, msk));
      mx1 = fmaxf(mx1, __shfl_xor(mx1, msk));
    }
    if (tid == 0) {
      for (int b = 0; b < m; ++b) {
        float tmn = 1e30f, tmx = -1e30f;
        for (int tt = 0; tt < T_; ++tt) {
          float v = tg[b*T_ + tt];
          tmn = fminf(tmn, v); tmx = fmaxf(tmx, v);
        }
        st[b][0] = tmn; st[b][1] = mn0; st[b][2] = mn1;
        st[b][3] = (tmx - tmn) / (float)(T_ - 1);
        st[b][4] = (mx0 - mn0) / (float)(N0_ - 1);
        st[b][5] = (mx1 - mn1) / (float)(N1_ - 1);
      }
    }
  }
  __syncthreads();
  int idx = bid * 256 + tid;
  if (idx < tot_xg) {                       // x_grid
    int sp = idx & (SP_ - 1);
    int bt = idx >> 10;
    out[idx*3 + 0] = tg[bt];
    out[idx*3 + 1] = grid[sp*2 + 0];
    out[idx*3 + 2] = grid[sp*2 + 1];
  }
  if (idx < m*n) {                          // assign
    int b = idx / n;
    int j = idx - b*n;
    const float* s = st[b];
    float xt = x[(size_t)idx*3 + 0], x0 = x[(size_t)idx*3 + 1], x1 = x[(size_t)idx*3 + 2];
    float m0 = floorf((xt - s[0] + s[3]*0.5f) / s[3]);
    float m1 = floorf((x0 - s[1] + s[4]*0.5f) / s[4]);
    float m2 = floorf((x1 - s[2] + s[5]*0.5f) / s[5]);
    m0 = fminf(fmaxf(m0, 0.f), (float)(T_ - 1));
    m1 = fminf(fmaxf(m1, 0.f), (float)(N0_ - 1));
    m2 = fminf(fmaxf(m2, 0.f), (float)(N1_ - 1));
    int sc = (int)m0 * SP_ + (int)m1 * N1_ + (int)m2;
    int cg = b * S_ + sc;
    int old = atomicAdd(&counts[cg], 1);
    if (old < P_) cell_raw[(size_t)cg * P_ + old] = j;
  }
}

// ============ fp32-A GEMM body: C[M,N] = cvt_bf16(A[M,256]) @ BT[N,256]^T ==================
// 512 thr / 8 waves, tile 128x128, BK=32 (8 kt). A staged fp32 (2x16KB LDS), B bf16
// (2x8KB), 48KB total -> 3 blocks/CU. DMA: 3 insts/wave/kt, pre-swizzled source + linear
// dest (A: 16B-granule ^ row&7; B: ^ col&3). Counted vmcnt(3); raw s_barrier. f2bf on the
// ds_read->fragment path.
template <typename OutT>
__device__ __forceinline__ void gemm_f32a_body(const float* __restrict__ A,
                                               const unsigned short* __restrict__ BT,
                                               OutT* __restrict__ C,
                                               int CP, int ldc, int L, int tid) {
  __shared__ float Af[2][128 * 32];
  __shared__ unsigned short Bf[2][128 * 32];
  int rp = L / CP, cp = L - rp * CP;

  int wid = tid >> 6, lane = tid & 63, l15 = lane & 15, slot = lane >> 4;
  int wr = (wid >> 2) * 64, wc = (wid & 3) * 32;   // wave tile 64x32

  // A staging: 2 DMAs/wave (8 rows each). lane: r = l>>3 (row in 8-group), g = l&7 (16B granule)
  int ar = lane >> 3, ag = lane & 7;
  const float* aSrc0 = A + (size_t)(rp * 128 + wid * 16 + ar) * 256 + ((ag ^ ar) << 2);
  const float* aSrc1 = aSrc0 + 8 * 256;
  // B staging: 1 DMA/wave (16 rows). lane: r = l>>2, g = l&3 (16B granule = 8 bf16)
  int br = lane >> 2, bg = lane & 3;
  const unsigned short* bSrc = BT + (size_t)(cp * 128 + wid * 16 + br) * 256 + ((bg ^ (br & 3)) << 3);

#define STAGEF(b, kt) do { \
    gl_lds16(aSrc0 + (kt) * 32, &Af[b][(wid * 16    ) * 32]); \
    gl_lds16(aSrc1 + (kt) * 32, &Af[b][(wid * 16 + 8) * 32]); \
    gl_lds16(bSrc  + (kt) * 32, &Bf[b][(wid * 16    ) * 32]); \
  } while (0)

  f32x4 acc[4][2] = {};
  STAGEF(0, 0);

#pragma unroll
  for (int kt = 0; kt < 8; ++kt) {
    int b = kt & 1;
    if (kt < 7) STAGEF(b ^ 1, kt + 1);
    if (kt < 7) asm volatile("s_waitcnt vmcnt(3)" ::: "memory");
    else        asm volatile("s_waitcnt vmcnt(0)" ::: "memory");
    __builtin_amdgcn_s_barrier();
    asm volatile("" ::: "memory");
    short8 afr[4], bfr[2];
#pragma unroll
    for (int mm = 0; mm < 4; ++mm) {
      int row = wr + mm * 16 + l15;
      int q0 = (2 * slot) ^ (row & 7);
      int q1 = (2 * slot + 1) ^ (row & 7);
      f32x4 a0 = *(const f32x4*)&Af[b][row * 32 + q0 * 4];
      f32x4 a1 = *(const f32x4*)&Af[b][row * 32 + q1 * 4];
      short8 af;
      af[0]=f2bf(a0[0]); af[1]=f2bf(a0[1]); af[2]=f2bf(a0[2]); af[3]=f2bf(a0[3]);
      af[4]=f2bf(a1[0]); af[5]=f2bf(a1[1]); af[6]=f2bf(a1[2]); af[7]=f2bf(a1[3]);
      afr[mm] = af;
    }
#pragma unroll
    for (int nn = 0; nn < 2; ++nn) {
      int col = wc + nn * 16 + l15;
      int q = slot ^ (col & 3);
      bfr[nn] = *(const short8*)&Bf[b][col * 32 + q * 8];
    }
#pragma unroll
    for (int mm = 0; mm < 4; ++mm)
#pragma unroll
      for (int nn = 0; nn < 2; ++nn)
        acc[mm][nn] = __builtin_amdgcn_mfma_f32_16x16x32_bf16(afr[mm], bfr[nn], acc[mm][nn], 0, 0, 0);
    asm volatile("" ::: "memory");
    __builtin_amdgcn_s_barrier();
    asm volatile("" ::: "memory");
  }
#undef STAGEF

  // ---- epilogue: C/D layout col=lane&15, row=(lane>>4)*4+j ----
#pragma unroll
  for (int mm = 0; mm < 4; ++mm) {
#pragma unroll
    for (int nn = 0; nn < 2; ++nn) {
      int grow0 = rp * 128 + wr + mm * 16 + slot * 4;
      int gcol  = cp * 128 + wc + nn * 16 + l15;
#pragma unroll
      for (int j = 0; j < 4; ++j) {
        size_t o = (size_t)(grow0 + j) * ldc + gcol;
        if constexpr (__is_same(OutT, float)) C[o] = acc[mm][nn][j];
        else                                  C[o] = __float2bfloat16(acc[mm][nn][j]);
      }
    }
  }
}

// kv projection: kv[m*n,512] = z @ [Wk|Wv], fp32 A streamed directly
__global__ __launch_bounds__(512) void gemm_kv(const float* __restrict__ z,
                                               const unsigned short* __restrict__ BT,
                                               __hip_bfloat16* __restrict__ kv) {
  int nb = gridDim.x, bid = blockIdx.x;
  int L = (bid & 7) * (nb >> 3) + (bid >> 3);   // XCD-chunked (nb=2048 %8==0)
  gemm_f32a_body<__hip_bfloat16>(z, BT, kv, 4, 512, L, threadIdx.x);
}

// ============ phase3: [0..48) latent GEMM (fp32 A) | [48..112) finalize ====================
__global__ __launch_bounds__(512) void phase3(const float* __restrict__ latents,
                                              const unsigned short* __restrict__ wT,
                                              float* __restrict__ lat,
                                              const int* __restrict__ counts,
                                              int* __restrict__ cell_raw,
                                              int* __restrict__ pts2, int total) {
  int bid = blockIdx.x;
  if (bid < 48) {
    gemm_f32a_body<float>(latents, wT, lat, 6, 768, bid, threadIdx.x);
    return;
  }
  int cg = (bid - 48) * 512 + threadIdx.x;
  if (cg >= total) return;
  int cnt = counts[cg];
  int stored = cnt < P_ ? cnt : P_;
  int eff = cnt < (P_ - 1) ? cnt : (P_ - 1);
  int* p = cell_raw + (size_t)cg * P_;
  for (int i = 1; i < stored; ++i) {   // insertion sort ascending (original index order)
    int key = p[i]; int j = i - 1;
    while (j >= 0 && p[j] > key) { p[j+1] = p[j]; --j; }
    p[j+1] = key;
  }
  int* o = pts2 + (size_t)cg * P_;
  o[0] = eff;
  for (int i = 0; i < eff; ++i) o[1 + i] = p[i];
}

// ============ bf16-A global_load_lds GEMM (Wo projection) ==================================
template <typename OutT>
__global__ __launch_bounds__(512, 4) void gemm_g2l(const unsigned short* __restrict__ A,
                                                   const unsigned short* __restrict__ BT,
                                                   OutT* __restrict__ C,
                                                   int M, int CP, int ldc) {
  __shared__ unsigned short lds[4][128 * 64];   // [buf*2 + (0=A,1=B)][row*64 + k]
  int tid = threadIdx.x;
  int nb = gridDim.x, bid = blockIdx.x;
  int L = bid;
  if ((nb & 7) == 0) L = (bid & 7) * (nb >> 3) + (bid >> 3);   // XCD-chunked swizzle
  int rp = L / CP, cp = L - rp * CP;

  int wid = tid >> 6, lane = tid & 63, l15 = lane & 15, slot = lane >> 4;
  int wr = (wid >> 2) * 64, wc = (wid & 3) * 32;   // wave tile 64x32

  int r8 = lane >> 3, k8 = lane & 7;
  int colsw = (k8 ^ r8) << 3;
  const unsigned short* ga0 = A  + (size_t)(rp * 128 + wid * 16 + r8) * 256 + colsw;
  const unsigned short* gb0 = BT + (size_t)(cp * 128 + wid * 16 + r8) * 256 + colsw;

#define STAGE(b, kt) do { \
    const unsigned short* ga = ga0 + (kt) * 64; \
    const unsigned short* gb = gb0 + (kt) * 64; \
    gl_lds16(ga,           &lds[(b)*2    ][(wid*16    ) * 64]); \
    gl_lds16(ga + 8*256,   &lds[(b)*2    ][(wid*16 + 8) * 64]); \
    gl_lds16(gb,           &lds[(b)*2 + 1][(wid*16    ) * 64]); \
    gl_lds16(gb + 8*256,   &lds[(b)*2 + 1][(wid*16 + 8) * 64]); \
  } while (0)

  f32x4 acc[4][2] = {};
  STAGE(0, 0);

#pragma unroll
  for (int kt = 0; kt < 4; ++kt) {
    int b = kt & 1;
    if (kt < 3) STAGE(b ^ 1, kt + 1);   // in flight across this kt's compute
    if (kt < 3) asm volatile("s_waitcnt vmcnt(4)" ::: "memory");
    else        asm volatile("s_waitcnt vmcnt(0)" ::: "memory");
    __builtin_amdgcn_s_barrier();
    asm volatile("" ::: "memory");
    const unsigned short* As = lds[b*2];
    const unsigned short* Bs = lds[b*2 + 1];
#pragma unroll
    for (int kf = 0; kf < 2; ++kf) {
      short8 afr[4], bfr[2];
      int kg = kf * 4 + slot;
      int sx = kg ^ (l15 & 7);
#pragma unroll
      for (int mm = 0; mm < 4; ++mm) {
        int row = wr + mm * 16 + l15;
        afr[mm] = *(const short8*)&As[row * 64 + (sx << 3)];
      }
#pragma unroll
      for (int nn = 0; nn < 2; ++nn) {
        int col = wc + nn * 16 + l15;
        bfr[nn] = *(const short8*)&Bs[col * 64 + (sx << 3)];
      }
#pragma unroll
      for (int mm = 0; mm < 4; ++mm)
#pragma unroll
        for (int nn = 0; nn < 2; ++nn)
          acc[mm][nn] = __builtin_amdgcn_mfma_f32_16x16x32_bf16(afr[mm], bfr[nn], acc[mm][nn], 0, 0, 0);
    }
    asm volatile("" ::: "memory");
    __builtin_amdgcn_s_barrier();
    asm volatile("" ::: "memory");
  }
#undef STAGE

#pragma unroll
  for (int mm = 0; mm < 4; ++mm) {
#pragma unroll
    for (int nn = 0; nn < 2; ++nn) {
      int grow0 = rp * 128 + wr + mm * 16 + slot * 4;
      int gcol  = cp * 128 + wc + nn * 16 + l15;
#pragma unroll
      for (int j = 0; j < 4; ++j) {
        size_t o = (size_t)(grow0 + j) * ldc + gcol;
        if constexpr (__is_same(OutT, float)) C[o] = acc[mm][nn][j];
        else                                  C[o] = __float2bfloat16(acc[mm][nn][j]);
      }
    }
  }
}

// ---------------- masked cross-attention: one wave per cell, online softmax ---------------
__global__ __launch_bounds__(256) void attn_kernel(
    const float* __restrict__ lat,          // [1024][768]  q|k|v
    const __hip_bfloat16* __restrict__ kv,  // [m*n][512]   k|v
    const int* __restrict__ pts2,           // [MS][16]: w0=eff, w1..15 sorted pt indices
    __hip_bfloat16* __restrict__ attn_out, int n) {
  const float scale = 0.17677669529663687f;  // 1/sqrt(32)
  int wid = threadIdx.x >> 6;
  int lane = threadIdx.x & 63;
  int cellg = blockIdx.x * 4 + wid;
  int b = cellg >> 13;                 // S_=8192, cells per batch
  int c = cellg & (SP_ - 1);           // spatial index -> latent row
  int d0 = lane << 2;                  // 4 dims per lane

  const int* pp = pts2 + (size_t)cellg * P_;
  int4 h0 = *(const int4*)pp;          // eff, pt0, pt1, pt2 (broadcast load)
  int eff = h0.x;

  const float* latc = lat + c * 768 + d0;
  float4 q  = *(const float4*)latc;
  float4 kl = *(const float4*)(latc + 256);
  float4 vl = *(const float4*)(latc + 512);

  // grid-token logit -> init online-softmax state
  float part = q.x*kl.x + q.y*kl.y + q.z*kl.z + q.w*kl.w;
  part += __shfl_xor(part, 1);
  part += __shfl_xor(part, 2);
  part += __shfl_xor(part, 4);         // head-local (8 lanes = 32 dims)
  float mx = part * scale;
  float ssum = 1.f;
  float4 acc = vl;

  const unsigned short* kvp = (const unsigned short*)kv;
  size_t bbase = (size_t)b * n;

  int pt[4]; pt[0] = h0.y; pt[1] = h0.z; pt[2] = h0.w; pt[3] = 0;
  int done = 0, cap = 3;
  while (done < eff) {
    int np = eff - done; if (np > cap) np = cap;
    ushort4 kr[4], vr[4];
#pragma unroll
    for (int i = 0; i < 4; ++i) if (i < np) {
      size_t row = (bbase + (size_t)pt[i]) * 512;
      kr[i] = *(const ushort4*)(kvp + row + d0);
      vr[i] = *(const ushort4*)(kvp + row + 256 + d0);
    }
#pragma unroll
    for (int i = 0; i < 4; ++i) if (i < np) {
      float p = q.x*bf2f(kr[i].x) + q.y*bf2f(kr[i].y) + q.z*bf2f(kr[i].z) + q.w*bf2f(kr[i].w);
      p += __shfl_xor(p, 1);
      p += __shfl_xor(p, 2);
      p += __shfl_xor(p, 4);
      p *= scale;
      float m2 = fmaxf(mx, p);
      float corr = __expf(mx - m2);
      float e = __expf(p - m2);
      ssum = ssum * corr + e;
      acc.x = acc.x * corr + e * bf2f(vr[i].x);
      acc.y = acc.y * corr + e * bf2f(vr[i].y);
      acc.z = acc.z * corr + e * bf2f(vr[i].z);
      acc.w = acc.w * corr + e * bf2f(vr[i].w);
      mx = m2;
    }
    done += np;
    cap = 4;
    if (done < eff) {
      int4 h = *(const int4*)(pp + 1 + done);   // done in {3,7,11} -> aligned
      pt[0] = h.x; pt[1] = h.y; pt[2] = h.z; pt[3] = h.w;
    }
  }
  float inv = 1.f / ssum;
  ushort4 o;
  o.x = f2bf(acc.x * inv); o.y = f2bf(acc.y * inv);
  o.z = f2bf(acc.z * inv); o.w = f2bf(acc.w * inv);
  *(ushort4*)((unsigned short*)attn_out + (size_t)cellg * E_ + d0) = o;
}

// -------------------------------------------------------------------------------------------
extern "C" void kernel_launch(void* const* d_in, const int* in_sizes, int n_in,
                              void* d_out, int out_size, void* d_ws, size_t ws_size,
                              hipStream_t stream) {
  const float* x       = (const float*)d_in[0];
  const float* z       = (const float*)d_in[1];
  const float* tg      = (const float*)d_in[2];
  const float* latents = (const float*)d_in[3];
  const float* grid    = (const float*)d_in[4];
  const float* Wq      = (const float*)d_in[5];
  const float* Wk      = (const float*)d_in[6];
  const float* Wv      = (const float*)d_in[7];
  const float* Wo      = (const float*)d_in[8];

  int m = in_sizes[2] / T_;              // 4
  int n = in_sizes[1] / (m * E_);        // 16384
  int MS = m * S_;                       // 32768
  float* out = (float*)d_out;
  int tot_xg = m * T_ * SP_;             // 32768 grid sites

  // ---- workspace carve (256B aligned) ----
  char* w = (char*)d_ws;
  auto alloc = [&](size_t bytes) { char* p = w; w += (bytes + 255) & ~(size_t)255; return p; };
  int*   counts     = (int*)  alloc((size_t)MS * 4);
  int*   cell_raw   = (int*)  alloc((size_t)MS * P_ * 4);
  int*   pts2       = (int*)  alloc((size_t)MS * P_ * 4);
  unsigned short* wT = (unsigned short*)alloc((size_t)1024 * 256 * 2);
  float* lat        = (float*)alloc((size_t)SP_ * 768 * 4);
  __hip_bfloat16* kv       = (__hip_bfloat16*)alloc((size_t)m * n * 512 * 2);
  __hip_bfloat16* attn_out = (__hip_bfloat16*)alloc((size_t)MS * E_ * 2);

  // 0) zero the atomic counters
  (void)hipMemsetAsync(counts, 0, (size_t)MS * 4, stream);

  // 1) stats + x_grid + assign | weight transpose   (256 + 64 blocks)
  prep_assign<<<320, 256, 0, stream>>>(x, tg, grid, out, counts, cell_raw,
                                       Wq, Wk, Wv, Wo, wT, m, n, tot_xg);

  // 2) latent GEMM (fp32 A, 48 blocks) | finalize (64 blocks x 512 cells)
  phase3<<<112, 512, 0, stream>>>(latents, wT, lat, counts, cell_raw, pts2, MS);

  // 3) point projections: kv[m*n,512] = z @ [Wk|Wv], fp32 A streamed (512 rp x 4 cp)
  gemm_kv<<<2048, 512, 0, stream>>>(z, wT + (size_t)256*256, kv);

  // 4) attention: one wave per cell
  attn_kernel<<<MS/4, 256, 0, stream>>>(lat, kv, pts2, attn_out, n);

  // 5) output projection -> z_grid   (256 rp x 2 cp)
  gemm_g2l<float><<<512, 512, 0, stream>>>(
      (const unsigned short*)attn_out, wT + (size_t)768*256, out + (size_t)tot_xg * 3, MS, 2, 256);
}